// Round 8
// baseline (383.477 us; speedup 1.0000x reference)
//
#include <hip/hip_runtime.h>
#include <stdint.h>

#define NN 100000
#define NE 1600000
#define NBUCK 391            // ceil(NN/256)
#define CHUNK 4000
#define NPART (NE / CHUNK)   // 400, exact

typedef __attribute__((ext_vector_type(8))) __bf16 bf16x8;
typedef __attribute__((ext_vector_type(4))) float  f32x4;
typedef unsigned int uint;

static __device__ __forceinline__ float blo(uint u) {
    union { uint i; float f; } v; v.i = u << 16; return v.f;
}
static __device__ __forceinline__ float bhi(uint u) {
    union { uint i; float f; } v; v.i = u & 0xffff0000u; return v.f;
}
static __device__ __forceinline__ uint packbf(float a, float b) {
    union { __bf16 h[2]; uint u; } v;
    v.h[0] = (__bf16)a; v.h[1] = (__bf16)b;
    return v.u;
}

// ---------- CSR build: two-level LDS-histogram partition (no per-edge global atomics) ----------

__global__ void zero_ints(int* p, int n) {
    int i = blockIdx.x * blockDim.x + threadIdx.x;
    if (i < n) p[i] = 0;
}

__global__ __launch_bounds__(256) void coarse_hist(const int* __restrict__ src,
        const int* __restrict__ dst, int* __restrict__ cd, int* __restrict__ cs, int e)
{
    __shared__ int hd[NBUCK], hs[NBUCK];
    for (int t = threadIdx.x; t < NBUCK; t += 256) { hd[t] = 0; hs[t] = 0; }
    __syncthreads();
    for (int i = blockIdx.x * 256 + threadIdx.x; i < e; i += gridDim.x * 256) {
        atomicAdd(&hd[dst[i] >> 8], 1);
        atomicAdd(&hs[src[i] >> 8], 1);
    }
    __syncthreads();
    for (int t = threadIdx.x; t < NBUCK; t += 256) {
        if (hd[t]) atomicAdd(&cd[t], hd[t]);
        if (hs[t]) atomicAdd(&cs[t], hs[t]);
    }
}

__global__ __launch_bounds__(512) void scan_coarse(const int* __restrict__ cd,
        const int* __restrict__ cs, int* __restrict__ offd, int* __restrict__ offs,
        int* __restrict__ curd, int* __restrict__ curs, int* __restrict__ row_ptr,
        int n, int e)
{
    __shared__ int sh[512];
    int t = threadIdx.x;
    int v = (t < NBUCK) ? cd[t] : 0;
    sh[t] = v;
    __syncthreads();
    for (int o = 1; o < 512; o <<= 1) {
        int tv = (t >= o) ? sh[t - o] : 0;
        __syncthreads();
        sh[t] += tv;
        __syncthreads();
    }
    if (t < NBUCK) { int ex = sh[t] - v; offd[t] = ex; curd[t] = ex; }
    if (t == 0) { offd[NBUCK] = e; row_ptr[n] = e; }
    __syncthreads();
    v = (t < NBUCK) ? cs[t] : 0;
    sh[t] = v;
    __syncthreads();
    for (int o = 1; o < 512; o <<= 1) {
        int tv = (t >= o) ? sh[t - o] : 0;
        __syncthreads();
        sh[t] += tv;
        __syncthreads();
    }
    if (t < NBUCK) { int ex = sh[t] - v; offs[t] = ex; curs[t] = ex; }
    if (t == 0) offs[NBUCK] = e;
}

// partition edges by dst>>8 (packed 4B pairs) AND src values by src>>8 (bsrc), one pass
__global__ __launch_bounds__(256) void part_both(const int* __restrict__ src,
        const int* __restrict__ dst, int* __restrict__ curd, int* __restrict__ curs,
        uint* __restrict__ pairs, int* __restrict__ bsrc, int e)
{
    __shared__ int hd[NBUCK], hs[NBUCK], based[NBUCK], bases[NBUCK];
    int beg = blockIdx.x * CHUNK;
    int end = beg + CHUNK; if (end > e) end = e;
    for (int t = threadIdx.x; t < NBUCK; t += 256) { hd[t] = 0; hs[t] = 0; }
    __syncthreads();
    for (int i = beg + threadIdx.x; i < end; i += 256) {
        atomicAdd(&hd[dst[i] >> 8], 1);
        atomicAdd(&hs[src[i] >> 8], 1);
    }
    __syncthreads();
    for (int t = threadIdx.x; t < NBUCK; t += 256) {
        based[t] = hd[t] ? atomicAdd(&curd[t], hd[t]) : 0;
        bases[t] = hs[t] ? atomicAdd(&curs[t], hs[t]) : 0;
    }
    __syncthreads();
    for (int i = beg + threadIdx.x; i < end; i += 256) {
        int s = src[i], d = dst[i];
        int pd = atomicAdd(&based[d >> 8], 1);     // LDS atomic
        pairs[pd] = ((uint)(d & 255) << 24) | (uint)s;
        int ps = atomicAdd(&bases[s >> 8], 1);     // LDS atomic
        bsrc[ps] = s;
    }
}

// one block per bucket: dst phase (row_ptr, nd, CSR placement) then src phase (ns)
__global__ __launch_bounds__(256) void fine_both(const int* __restrict__ offd,
        const uint* __restrict__ pairs, const int* __restrict__ offs,
        const int* __restrict__ bsrc, int* __restrict__ row_ptr,
        float* __restrict__ nd, float* __restrict__ ns, int* __restrict__ csr, int n)
{
    __shared__ int h[256], sh[256], cur[256];
    int b = blockIdx.x;
    int t = threadIdx.x;
    int node = (b << 8) + t;
    // ---- dst phase ----
    int beg = offd[b], end = offd[b + 1];
    h[t] = 0;
    __syncthreads();
    for (int i = beg + t; i < end; i += 256)
        atomicAdd(&h[pairs[i] >> 24], 1);
    __syncthreads();
    int v = h[t];
    sh[t] = v;
    __syncthreads();
    for (int o = 1; o < 256; o <<= 1) {
        int tv = (t >= o) ? sh[t - o] : 0;
        __syncthreads();
        sh[t] += tv;
        __syncthreads();
    }
    int ex = sh[t] - v;
    if (node < n) {
        row_ptr[node] = beg + ex;
        nd[node] = rsqrtf((float)v + 1.0f);        // +1 self-loop
    }
    cur[t] = beg + ex;
    __syncthreads();
    for (int i = beg + t; i < end; i += 256) {
        uint pr = pairs[i];
        int pos = atomicAdd(&cur[pr >> 24], 1);    // LDS atomic
        csr[pos] = (int)(pr & 0x00FFFFFFu);
    }
    // ---- src phase ----
    h[t] = 0;
    __syncthreads();
    int sbeg = offs[b], send = offs[b + 1];
    for (int i = sbeg + t; i < send; i += 256)
        atomicAdd(&h[bsrc[i] & 255], 1);
    __syncthreads();
    if (node < n) ns[node] = rsqrtf((float)h[t] + 1.0f);
}

// ---------- layer-1 MFMA GEMM, f32 A via split-bf16: X@W ~= Xhi@Whi + Xlo@Whi + Xhi@Wlo ----------
template<int F, bool SCALE>
__global__ __launch_bounds__(256) void gemm_mfma(const float* __restrict__ X,
        const float* __restrict__ W, const float* __restrict__ rowscale,
        __bf16* __restrict__ xw, int nchunks)
{
    __shared__ __bf16 Whi[(F/16)*4*64*8];
    __shared__ __bf16 Wlo[(F/16)*4*64*8];
    for (int idx = threadIdx.x; idx < (F/16)*4*64; idx += 256) {
        int cb = idx >> 8;
        int kc = (idx >> 6) & 3;
        int ln = idx & 63;
        int col = cb*16 + (ln & 15);
        int kb  = kc*32 + (ln >> 4)*8;
        #pragma unroll
        for (int j = 0; j < 8; ++j) {
            float f = W[(size_t)(kb + j)*F + col];
            __bf16 h = (__bf16)f;
            Whi[idx*8 + j] = h;
            Wlo[idx*8 + j] = (__bf16)(f - (float)h);
        }
    }
    __syncthreads();
    const int lane = threadIdx.x & 63;
    const int m = lane & 15, q = lane >> 4;
    int c = blockIdx.x*4 + (threadIdx.x >> 6);
    if (c >= nchunks) return;
    int rbase = c*16;
    const float* xrow = X + (size_t)(rbase + m)*128;
    f32x4 acc[F/16];
    #pragma unroll
    for (int i = 0; i < F/16; ++i) acc[i] = (f32x4)0.f;
    #pragma unroll
    for (int kc = 0; kc < 4; ++kc) {
        int kb = kc*32 + q*8;
        float4 v0 = *(const float4*)(xrow + kb);
        float4 v1 = *(const float4*)(xrow + kb + 4);
        float xf[8] = {v0.x, v0.y, v0.z, v0.w, v1.x, v1.y, v1.z, v1.w};
        bf16x8 ahi, alo;
        #pragma unroll
        for (int j = 0; j < 8; ++j) {
            __bf16 h = (__bf16)xf[j];
            ahi[j] = h;
            alo[j] = (__bf16)(xf[j] - (float)h);
        }
        #pragma unroll
        for (int cb = 0; cb < F/16; ++cb) {
            bf16x8 bh = *(const bf16x8*)(Whi + ((cb*4 + kc)*64 + lane)*8);
            bf16x8 bl = *(const bf16x8*)(Wlo + ((cb*4 + kc)*64 + lane)*8);
            acc[cb] = __builtin_amdgcn_mfma_f32_16x16x32_bf16(ahi, bh, acc[cb], 0, 0, 0);
            acc[cb] = __builtin_amdgcn_mfma_f32_16x16x32_bf16(alo, bh, acc[cb], 0, 0, 0);
            acc[cb] = __builtin_amdgcn_mfma_f32_16x16x32_bf16(ahi, bl, acc[cb], 0, 0, 0);
        }
    }
    float s[4];
    #pragma unroll
    for (int reg = 0; reg < 4; ++reg)
        s[reg] = SCALE ? rowscale[rbase + q*4 + reg] : 1.0f;
    #pragma unroll
    for (int cb = 0; cb < F/16; ++cb)
        #pragma unroll
        for (int reg = 0; reg < 4; ++reg)
            xw[(size_t)(rbase + q*4 + reg)*F + cb*16 + m] = (__bf16)(acc[cb][reg] * s[reg]);
}

// ---------- layer-2 MFMA GEMM, bf16 A direct (2 MFMAs: A@Whi + A@Wlo) ----------
template<int F>
__global__ __launch_bounds__(256) void gemm_mfma_bf16(const __bf16* __restrict__ X,
        const float* __restrict__ W, __bf16* __restrict__ xw, int nchunks)
{
    __shared__ __bf16 Whi[(F/16)*4*64*8];
    __shared__ __bf16 Wlo[(F/16)*4*64*8];
    for (int idx = threadIdx.x; idx < (F/16)*4*64; idx += 256) {
        int cb = idx >> 8;
        int kc = (idx >> 6) & 3;
        int ln = idx & 63;
        int col = cb*16 + (ln & 15);
        int kb  = kc*32 + (ln >> 4)*8;
        #pragma unroll
        for (int j = 0; j < 8; ++j) {
            float f = W[(size_t)(kb + j)*F + col];
            __bf16 h = (__bf16)f;
            Whi[idx*8 + j] = h;
            Wlo[idx*8 + j] = (__bf16)(f - (float)h);
        }
    }
    __syncthreads();
    const int lane = threadIdx.x & 63;
    const int m = lane & 15, q = lane >> 4;
    int c = blockIdx.x*4 + (threadIdx.x >> 6);
    if (c >= nchunks) return;
    int rbase = c*16;
    const __bf16* xrow = X + (size_t)(rbase + m)*128;
    f32x4 acc[F/16];
    #pragma unroll
    for (int i = 0; i < F/16; ++i) acc[i] = (f32x4)0.f;
    #pragma unroll
    for (int kc = 0; kc < 4; ++kc) {
        int kb = kc*32 + q*8;
        bf16x8 a = *(const bf16x8*)(xrow + kb);      // 16 B contiguous bf16 load
        #pragma unroll
        for (int cb = 0; cb < F/16; ++cb) {
            bf16x8 bh = *(const bf16x8*)(Whi + ((cb*4 + kc)*64 + lane)*8);
            bf16x8 bl = *(const bf16x8*)(Wlo + ((cb*4 + kc)*64 + lane)*8);
            acc[cb] = __builtin_amdgcn_mfma_f32_16x16x32_bf16(a, bh, acc[cb], 0, 0, 0);
            acc[cb] = __builtin_amdgcn_mfma_f32_16x16x32_bf16(a, bl, acc[cb], 0, 0, 0);
        }
    }
    #pragma unroll
    for (int cb = 0; cb < F/16; ++cb)
        #pragma unroll
        for (int reg = 0; reg < 4; ++reg)
            xw[(size_t)(rbase + q*4 + reg)*F + cb*16 + m] = (__bf16)acc[cb][reg];
}

// ---------- layer-1 aggregate: one wave per node, quarter-wave (16 lanes x uint4) per edge row ----------
// epilogue writes h as BF16
__global__ __launch_bounds__(256) void agg_csr128(const int* __restrict__ row_ptr,
        const int* __restrict__ csr, const uint4* __restrict__ xw,
        const float* __restrict__ nd, const float* __restrict__ ns,
        const float* __restrict__ b, __bf16* __restrict__ out, int n)
{
    int r = blockIdx.x * 4 + (threadIdx.x >> 6);
    if (r >= n) return;
    const int lane = threadIdx.x & 63;
    const int q = lane >> 4, ql = lane & 15;
    int beg = row_ptr[r], end = row_ptr[r + 1];
    float a[8];
    if (q == 0) {                                   // self-loop row, quarter 0 only
        uint4 u = xw[(size_t)r * 16 + ql];
        a[0]=blo(u.x); a[1]=bhi(u.x); a[2]=blo(u.y); a[3]=bhi(u.y);
        a[4]=blo(u.z); a[5]=bhi(u.z); a[6]=blo(u.w); a[7]=bhi(u.w);
    } else {
        #pragma unroll
        for (int i = 0; i < 8; ++i) a[i] = 0.f;
    }
    int j = beg;
    for (; j + 32 <= end; j += 32) {                // 32 edges: 8 uint4 loads/lane in flight
        uint4 u[8];
        int sidx[8];
        #pragma unroll
        for (int k = 0; k < 8; ++k) sidx[k] = csr[j + 4*k + q];
        #pragma unroll
        for (int k = 0; k < 8; ++k) u[k] = xw[(size_t)sidx[k] * 16 + ql];
        #pragma unroll
        for (int k = 0; k < 8; ++k) {
            a[0]+=blo(u[k].x); a[1]+=bhi(u[k].x); a[2]+=blo(u[k].y); a[3]+=bhi(u[k].y);
            a[4]+=blo(u[k].z); a[5]+=bhi(u[k].z); a[6]+=blo(u[k].w); a[7]+=bhi(u[k].w);
        }
    }
    for (; j + 4 <= end; j += 4) {
        int s0 = csr[j + q];
        uint4 u0 = xw[(size_t)s0 * 16 + ql];
        a[0]+=blo(u0.x); a[1]+=bhi(u0.x); a[2]+=blo(u0.y); a[3]+=bhi(u0.y);
        a[4]+=blo(u0.z); a[5]+=bhi(u0.z); a[6]+=blo(u0.w); a[7]+=bhi(u0.w);
    }
    int rem = end - j;                              // 0..3
    if (q < rem) {
        int s0 = csr[j + q];
        uint4 u0 = xw[(size_t)s0 * 16 + ql];
        a[0]+=blo(u0.x); a[1]+=bhi(u0.x); a[2]+=blo(u0.y); a[3]+=bhi(u0.y);
        a[4]+=blo(u0.z); a[5]+=bhi(u0.z); a[6]+=blo(u0.w); a[7]+=bhi(u0.w);
    }
    #pragma unroll
    for (int i = 0; i < 8; ++i) {
        a[i] += __shfl_xor(a[i], 32);
        a[i] += __shfl_xor(a[i], 16);
    }
    if (q == 0) {
        float ndr = nd[r], nsr = ns[r];
        float4 b0 = *(const float4*)(b + ql * 8);
        float4 b1 = *(const float4*)(b + ql * 8 + 4);
        float o0 = fmaxf(a[0]*ndr + b0.x, 0.f) * nsr;
        float o1 = fmaxf(a[1]*ndr + b0.y, 0.f) * nsr;
        float o2 = fmaxf(a[2]*ndr + b0.z, 0.f) * nsr;
        float o3 = fmaxf(a[3]*ndr + b0.w, 0.f) * nsr;
        float o4 = fmaxf(a[4]*ndr + b1.x, 0.f) * nsr;
        float o5 = fmaxf(a[5]*ndr + b1.y, 0.f) * nsr;
        float o6 = fmaxf(a[6]*ndr + b1.z, 0.f) * nsr;
        float o7 = fmaxf(a[7]*ndr + b1.w, 0.f) * nsr;
        uint4 pk;
        pk.x = packbf(o0, o1);
        pk.y = packbf(o2, o3);
        pk.z = packbf(o4, o5);
        pk.w = packbf(o6, o7);
        ((uint4*)(out + (size_t)r * 128))[ql] = pk;
    }
}

// ---------- layer-2 aggregate: one wave per node, quarter-wave (16 lanes x uint2) per edge row ----------
__global__ __launch_bounds__(256) void agg_csr64(const int* __restrict__ row_ptr,
        const int* __restrict__ csr, const uint2* __restrict__ xw,
        const float* __restrict__ nd, const float* __restrict__ b,
        float* __restrict__ out, int n)
{
    int r = blockIdx.x * 4 + (threadIdx.x >> 6);
    if (r >= n) return;
    const int lane = threadIdx.x & 63;
    const int q = lane >> 4, ql = lane & 15;
    int beg = row_ptr[r], end = row_ptr[r + 1];
    float a[4];
    if (q == 0) {                                   // self-loop row
        uint2 u = xw[(size_t)r * 16 + ql];
        a[0]=blo(u.x); a[1]=bhi(u.x); a[2]=blo(u.y); a[3]=bhi(u.y);
    } else {
        #pragma unroll
        for (int i = 0; i < 4; ++i) a[i] = 0.f;
    }
    int j = beg;
    for (; j + 32 <= end; j += 32) {                // 32 edges: 8 uint2 loads/lane in flight
        uint2 u[8];
        int sidx[8];
        #pragma unroll
        for (int k = 0; k < 8; ++k) sidx[k] = csr[j + 4*k + q];
        #pragma unroll
        for (int k = 0; k < 8; ++k) u[k] = xw[(size_t)sidx[k] * 16 + ql];
        #pragma unroll
        for (int k = 0; k < 8; ++k) {
            a[0]+=blo(u[k].x); a[1]+=bhi(u[k].x); a[2]+=blo(u[k].y); a[3]+=bhi(u[k].y);
        }
    }
    for (; j + 4 <= end; j += 4) {
        int s0 = csr[j + q];
        uint2 u0 = xw[(size_t)s0 * 16 + ql];
        a[0]+=blo(u0.x); a[1]+=bhi(u0.x); a[2]+=blo(u0.y); a[3]+=bhi(u0.y);
    }
    int rem = end - j;
    if (q < rem) {
        int s0 = csr[j + q];
        uint2 u0 = xw[(size_t)s0 * 16 + ql];
        a[0]+=blo(u0.x); a[1]+=bhi(u0.x); a[2]+=blo(u0.y); a[3]+=bhi(u0.y);
    }
    #pragma unroll
    for (int i = 0; i < 4; ++i) {
        a[i] += __shfl_xor(a[i], 32);
        a[i] += __shfl_xor(a[i], 16);
    }
    if (q == 0) {
        float ndr = nd[r];
        float4 bb = *(const float4*)(b + ql * 4);
        float4 o;
        o.x = a[0]*ndr + bb.x;
        o.y = a[1]*ndr + bb.y;
        o.z = a[2]*ndr + bb.z;
        o.w = a[3]*ndr + bb.w;
        *(float4*)(out + (size_t)r * 64 + ql * 4) = o;
    }
}

extern "C" void kernel_launch(void* const* d_in, const int* in_sizes, int n_in,
                              void* d_out, int out_size, void* d_ws, size_t ws_size,
                              hipStream_t stream)
{
    const float* x  = (const float*)d_in[0];   // [N,128] f32
    const int* src  = (const int*)d_in[1];     // [E]
    const int* dst  = (const int*)d_in[2];     // [E]
    const float* W1 = (const float*)d_in[3];   // [128,128] f32
    const float* b1 = (const float*)d_in[4];   // [128] f32
    const float* W2 = (const float*)d_in[5];   // [128,64] f32
    const float* b2 = (const float*)d_in[6];   // [64] f32
    float* out = (float*)d_out;                // [N,64] f32

    const int n = NN, e = NE;
    const int nchunks = n / 16;                // 6250, exact
    const int gemm_grid = (nchunks + 3) / 4;   // 1563: one chunk per wave

    // workspace layout
    char* p = (char*)d_ws;
    float* ns      = (float*)p; p += (size_t)n * 4;
    float* nd      = (float*)p; p += (size_t)n * 4;
    int*   row_ptr = (int*)p;   p += (size_t)(n + 1) * 4;
    int*   cd      = (int*)p;   p += (size_t)NBUCK * 4;     // cd,cs adjacent: zeroed together
    int*   cs      = (int*)p;   p += (size_t)NBUCK * 4;
    int*   offd    = (int*)p;   p += (size_t)(NBUCK + 1) * 4;
    int*   offs    = (int*)p;   p += (size_t)(NBUCK + 1) * 4;
    int*   curd    = (int*)p;   p += (size_t)NBUCK * 4;
    int*   curs    = (int*)p;   p += (size_t)NBUCK * 4;
    int*   csr     = (int*)p;   p += (size_t)e * 4;
    p = (char*)(((uintptr_t)p + 255) & ~(uintptr_t)255);
    __bf16* bufA   = (__bf16*)p; p += (size_t)128 * n * 2;  // xw1 bf16, then xw2 bf16
    p = (char*)(((uintptr_t)p + 255) & ~(uintptr_t)255);
    __bf16* bufB   = (__bf16*)p;                             // h bf16 [N,128]
    uint*  pairs   = (uint*)bufB;                            // build-phase only (6.4 MB)
    int*   bsrc    = (int*)bufA;                             // build-phase only (6.4 MB)

    zero_ints<<<(2 * NBUCK + 255) / 256, 256, 0, stream>>>(cd, 2 * NBUCK);
    coarse_hist<<<256, 256, 0, stream>>>(src, dst, cd, cs, e);
    scan_coarse<<<1, 512, 0, stream>>>(cd, cs, offd, offs, curd, curs, row_ptr, n, e);
    part_both<<<NPART, 256, 0, stream>>>(src, dst, curd, curs, pairs, bsrc, e);
    fine_both<<<NBUCK, 256, 0, stream>>>(offd, pairs, offs, bsrc, row_ptr, nd, ns, csr, n);

    // layer 1: xw1 = bf16((x @ W1) * ns) ; h = bf16(relu((xw1[r]+sum nbr)*nd + b1) * ns)
    gemm_mfma<128, true><<<gemm_grid, 256, 0, stream>>>(x, W1, ns, bufA, nchunks);
    agg_csr128<<<(n + 3) / 4, 256, 0, stream>>>(row_ptr, csr, (const uint4*)bufA, nd, ns, b1, bufB, n);

    // layer 2: xw2 = bf16(h @ W2) ; out = (xw2[r]+sum nbr)*nd + b2
    gemm_mfma_bf16<64><<<gemm_grid, 256, 0, stream>>>(bufB, W2, bufA, nchunks);
    agg_csr64<<<(n + 3) / 4, 256, 0, stream>>>(row_ptr, csr, (const uint2*)bufA, nd, b2, out, n);
}

// Round 9
// 312.031 us; speedup vs baseline: 1.2290x; 1.2290x over previous
//
#include <hip/hip_runtime.h>
#include <stdint.h>

#define NN 100000
#define NE 1600000
#define NBUCK 391            // ceil(NN/256)
#define CHUNK 4000
#define NPART (NE / CHUNK)   // 400, exact

typedef __attribute__((ext_vector_type(8))) __bf16 bf16x8;
typedef __attribute__((ext_vector_type(4))) float  f32x4;
typedef unsigned int uint;

static __device__ __forceinline__ float blo(uint u) {
    union { uint i; float f; } v; v.i = u << 16; return v.f;
}
static __device__ __forceinline__ float bhi(uint u) {
    union { uint i; float f; } v; v.i = u & 0xffff0000u; return v.f;
}
static __device__ __forceinline__ uint packbf(float a, float b) {
    union { __bf16 h[2]; uint u; } v;
    v.h[0] = (__bf16)a; v.h[1] = (__bf16)b;
    return v.u;
}

// ---------- CSR build: two-level LDS-histogram partition ----------

__global__ void zero_ints(int* p, int n) {
    int i = blockIdx.x * blockDim.x + threadIdx.x;
    if (i < n) p[i] = 0;
}

// uint4 edge loads; two LDS histogram copies (by wave parity) to cut conflicts
__global__ __launch_bounds__(256) void coarse_hist(const int4* __restrict__ src4,
        const int4* __restrict__ dst4, int* __restrict__ cd, int* __restrict__ cs, int e4)
{
    __shared__ int hd[2][NBUCK], hs[2][NBUCK];
    for (int t = threadIdx.x; t < NBUCK; t += 256) {
        hd[0][t] = 0; hd[1][t] = 0; hs[0][t] = 0; hs[1][t] = 0;
    }
    __syncthreads();
    const int c = (threadIdx.x >> 6) & 1;
    for (int i = blockIdx.x * 256 + threadIdx.x; i < e4; i += gridDim.x * 256) {
        int4 d = dst4[i], s = src4[i];
        atomicAdd(&hd[c][d.x >> 8], 1); atomicAdd(&hd[c][d.y >> 8], 1);
        atomicAdd(&hd[c][d.z >> 8], 1); atomicAdd(&hd[c][d.w >> 8], 1);
        atomicAdd(&hs[c][s.x >> 8], 1); atomicAdd(&hs[c][s.y >> 8], 1);
        atomicAdd(&hs[c][s.z >> 8], 1); atomicAdd(&hs[c][s.w >> 8], 1);
    }
    __syncthreads();
    for (int t = threadIdx.x; t < NBUCK; t += 256) {
        int vd = hd[0][t] + hd[1][t];
        int vs = hs[0][t] + hs[1][t];
        if (vd) atomicAdd(&cd[t], vd);
        if (vs) atomicAdd(&cs[t], vs);
    }
}

__global__ __launch_bounds__(512) void scan_coarse(const int* __restrict__ cd,
        const int* __restrict__ cs, int* __restrict__ offd, int* __restrict__ offs,
        int* __restrict__ curd, int* __restrict__ curs, int* __restrict__ row_ptr,
        int n, int e)
{
    __shared__ int sh[512];
    int t = threadIdx.x;
    int v = (t < NBUCK) ? cd[t] : 0;
    sh[t] = v;
    __syncthreads();
    for (int o = 1; o < 512; o <<= 1) {
        int tv = (t >= o) ? sh[t - o] : 0;
        __syncthreads();
        sh[t] += tv;
        __syncthreads();
    }
    if (t < NBUCK) { int ex = sh[t] - v; offd[t] = ex; curd[t] = ex; }
    if (t == 0) { offd[NBUCK] = e; row_ptr[n] = e; }
    __syncthreads();
    v = (t < NBUCK) ? cs[t] : 0;
    sh[t] = v;
    __syncthreads();
    for (int o = 1; o < 512; o <<= 1) {
        int tv = (t >= o) ? sh[t - o] : 0;
        __syncthreads();
        sh[t] += tv;
        __syncthreads();
    }
    if (t < NBUCK) { int ex = sh[t] - v; offs[t] = ex; curs[t] = ex; }
    if (t == 0) offs[NBUCK] = e;
}

// partition edges by dst>>8 (packed 4B pairs) AND src values by src>>8 (bsrc), one pass
__global__ __launch_bounds__(256) void part_both(const int* __restrict__ src,
        const int* __restrict__ dst, int* __restrict__ curd, int* __restrict__ curs,
        uint* __restrict__ pairs, int* __restrict__ bsrc, int e)
{
    __shared__ int hd[NBUCK], hs[NBUCK], based[NBUCK], bases[NBUCK];
    int beg = blockIdx.x * CHUNK;
    int end = beg + CHUNK; if (end > e) end = e;
    for (int t = threadIdx.x; t < NBUCK; t += 256) { hd[t] = 0; hs[t] = 0; }
    __syncthreads();
    for (int i = beg + threadIdx.x * 4; i + 4 <= end; i += 1024) {
        int4 d = *(const int4*)(dst + i);
        int4 s = *(const int4*)(src + i);
        atomicAdd(&hd[d.x >> 8], 1); atomicAdd(&hd[d.y >> 8], 1);
        atomicAdd(&hd[d.z >> 8], 1); atomicAdd(&hd[d.w >> 8], 1);
        atomicAdd(&hs[s.x >> 8], 1); atomicAdd(&hs[s.y >> 8], 1);
        atomicAdd(&hs[s.z >> 8], 1); atomicAdd(&hs[s.w >> 8], 1);
    }
    __syncthreads();
    for (int t = threadIdx.x; t < NBUCK; t += 256) {
        based[t] = hd[t] ? atomicAdd(&curd[t], hd[t]) : 0;
        bases[t] = hs[t] ? atomicAdd(&curs[t], hs[t]) : 0;
    }
    __syncthreads();
    for (int i = beg + threadIdx.x; i < end; i += 256) {
        int s = src[i], d = dst[i];
        int pd = atomicAdd(&based[d >> 8], 1);     // LDS atomic
        pairs[pd] = ((uint)(d & 255) << 24) | (uint)s;
        int ps = atomicAdd(&bases[s >> 8], 1);     // LDS atomic
        bsrc[ps] = s;
    }
}

// one block per bucket: dst phase (row_ptr, nd, CSR placement) then src phase (ns)
__global__ __launch_bounds__(256) void fine_both(const int* __restrict__ offd,
        const uint* __restrict__ pairs, const int* __restrict__ offs,
        const int* __restrict__ bsrc, int* __restrict__ row_ptr,
        float* __restrict__ nd, float* __restrict__ ns, int* __restrict__ csr, int n)
{
    __shared__ int h[256], sh[256], cur[256];
    int b = blockIdx.x;
    int t = threadIdx.x;
    int node = (b << 8) + t;
    // ---- dst phase ----
    int beg = offd[b], end = offd[b + 1];
    h[t] = 0;
    __syncthreads();
    for (int i = beg + t; i < end; i += 256)
        atomicAdd(&h[pairs[i] >> 24], 1);
    __syncthreads();
    int v = h[t];
    sh[t] = v;
    __syncthreads();
    for (int o = 1; o < 256; o <<= 1) {
        int tv = (t >= o) ? sh[t - o] : 0;
        __syncthreads();
        sh[t] += tv;
        __syncthreads();
    }
    int ex = sh[t] - v;
    if (node < n) {
        row_ptr[node] = beg + ex;
        nd[node] = rsqrtf((float)v + 1.0f);        // +1 self-loop
    }
    cur[t] = beg + ex;
    __syncthreads();
    for (int i = beg + t; i < end; i += 256) {
        uint pr = pairs[i];
        int pos = atomicAdd(&cur[pr >> 24], 1);    // LDS atomic
        csr[pos] = (int)(pr & 0x00FFFFFFu);
    }
    // ---- src phase ----
    h[t] = 0;
    __syncthreads();
    int sbeg = offs[b], send = offs[b + 1];
    for (int i = sbeg + t; i < send; i += 256)
        atomicAdd(&h[bsrc[i] & 255], 1);
    __syncthreads();
    if (node < n) ns[node] = rsqrtf((float)h[t] + 1.0f);
}

// ---------- layer-1 MFMA GEMM, f32 A via split-bf16 ----------
template<int F, bool SCALE>
__global__ __launch_bounds__(256) void gemm_mfma(const float* __restrict__ X,
        const float* __restrict__ W, const float* __restrict__ rowscale,
        __bf16* __restrict__ xw, int nchunks)
{
    __shared__ __bf16 Whi[(F/16)*4*64*8];
    __shared__ __bf16 Wlo[(F/16)*4*64*8];
    for (int idx = threadIdx.x; idx < (F/16)*4*64; idx += 256) {
        int cb = idx >> 8;
        int kc = (idx >> 6) & 3;
        int ln = idx & 63;
        int col = cb*16 + (ln & 15);
        int kb  = kc*32 + (ln >> 4)*8;
        #pragma unroll
        for (int j = 0; j < 8; ++j) {
            float f = W[(size_t)(kb + j)*F + col];
            __bf16 h = (__bf16)f;
            Whi[idx*8 + j] = h;
            Wlo[idx*8 + j] = (__bf16)(f - (float)h);
        }
    }
    __syncthreads();
    const int lane = threadIdx.x & 63;
    const int m = lane & 15, q = lane >> 4;
    int c = blockIdx.x*4 + (threadIdx.x >> 6);
    if (c >= nchunks) return;
    int rbase = c*16;
    const float* xrow = X + (size_t)(rbase + m)*128;
    f32x4 acc[F/16];
    #pragma unroll
    for (int i = 0; i < F/16; ++i) acc[i] = (f32x4)0.f;
    #pragma unroll
    for (int kc = 0; kc < 4; ++kc) {
        int kb = kc*32 + q*8;
        float4 v0 = *(const float4*)(xrow + kb);
        float4 v1 = *(const float4*)(xrow + kb + 4);
        float xf[8] = {v0.x, v0.y, v0.z, v0.w, v1.x, v1.y, v1.z, v1.w};
        bf16x8 ahi, alo;
        #pragma unroll
        for (int j = 0; j < 8; ++j) {
            __bf16 h = (__bf16)xf[j];
            ahi[j] = h;
            alo[j] = (__bf16)(xf[j] - (float)h);
        }
        #pragma unroll
        for (int cb = 0; cb < F/16; ++cb) {
            bf16x8 bh = *(const bf16x8*)(Whi + ((cb*4 + kc)*64 + lane)*8);
            bf16x8 bl = *(const bf16x8*)(Wlo + ((cb*4 + kc)*64 + lane)*8);
            acc[cb] = __builtin_amdgcn_mfma_f32_16x16x32_bf16(ahi, bh, acc[cb], 0, 0, 0);
            acc[cb] = __builtin_amdgcn_mfma_f32_16x16x32_bf16(alo, bh, acc[cb], 0, 0, 0);
            acc[cb] = __builtin_amdgcn_mfma_f32_16x16x32_bf16(ahi, bl, acc[cb], 0, 0, 0);
        }
    }
    float s[4];
    #pragma unroll
    for (int reg = 0; reg < 4; ++reg)
        s[reg] = SCALE ? rowscale[rbase + q*4 + reg] : 1.0f;
    #pragma unroll
    for (int cb = 0; cb < F/16; ++cb)
        #pragma unroll
        for (int reg = 0; reg < 4; ++reg)
            xw[(size_t)(rbase + q*4 + reg)*F + cb*16 + m] = (__bf16)(acc[cb][reg] * s[reg]);
}

// ---------- layer-2 MFMA GEMM, bf16 A direct (2 MFMAs) ----------
template<int F>
__global__ __launch_bounds__(256) void gemm_mfma_bf16(const __bf16* __restrict__ X,
        const float* __restrict__ W, __bf16* __restrict__ xw, int nchunks)
{
    __shared__ __bf16 Whi[(F/16)*4*64*8];
    __shared__ __bf16 Wlo[(F/16)*4*64*8];
    for (int idx = threadIdx.x; idx < (F/16)*4*64; idx += 256) {
        int cb = idx >> 8;
        int kc = (idx >> 6) & 3;
        int ln = idx & 63;
        int col = cb*16 + (ln & 15);
        int kb  = kc*32 + (ln >> 4)*8;
        #pragma unroll
        for (int j = 0; j < 8; ++j) {
            float f = W[(size_t)(kb + j)*F + col];
            __bf16 h = (__bf16)f;
            Whi[idx*8 + j] = h;
            Wlo[idx*8 + j] = (__bf16)(f - (float)h);
        }
    }
    __syncthreads();
    const int lane = threadIdx.x & 63;
    const int m = lane & 15, q = lane >> 4;
    int c = blockIdx.x*4 + (threadIdx.x >> 6);
    if (c >= nchunks) return;
    int rbase = c*16;
    const __bf16* xrow = X + (size_t)(rbase + m)*128;
    f32x4 acc[F/16];
    #pragma unroll
    for (int i = 0; i < F/16; ++i) acc[i] = (f32x4)0.f;
    #pragma unroll
    for (int kc = 0; kc < 4; ++kc) {
        int kb = kc*32 + q*8;
        bf16x8 a = *(const bf16x8*)(xrow + kb);
        #pragma unroll
        for (int cb = 0; cb < F/16; ++cb) {
            bf16x8 bh = *(const bf16x8*)(Whi + ((cb*4 + kc)*64 + lane)*8);
            bf16x8 bl = *(const bf16x8*)(Wlo + ((cb*4 + kc)*64 + lane)*8);
            acc[cb] = __builtin_amdgcn_mfma_f32_16x16x32_bf16(a, bh, acc[cb], 0, 0, 0);
            acc[cb] = __builtin_amdgcn_mfma_f32_16x16x32_bf16(a, bl, acc[cb], 0, 0, 0);
        }
    }
    #pragma unroll
    for (int cb = 0; cb < F/16; ++cb)
        #pragma unroll
        for (int reg = 0; reg < 4; ++reg)
            xw[(size_t)(rbase + q*4 + reg)*F + cb*16 + m] = (__bf16)acc[cb][reg];
}

// ---------- layer-1 aggregate: ONE QUARTER-WAVE (16 lanes) PER NODE ----------
// row = 16 lanes x uint4 (256 B). Each lane owns 8 columns end-to-end; no reduce.
// 4 nodes/wave, 4 gathers in flight per lane => 16 outstanding gathers/wave.
__global__ __launch_bounds__(256) void agg_csr128(const int* __restrict__ row_ptr,
        const int* __restrict__ csr, const uint4* __restrict__ xw,
        const float* __restrict__ nd, const float* __restrict__ ns,
        const float* __restrict__ b, __bf16* __restrict__ out, int n)
{
    int r = blockIdx.x * 16 + (threadIdx.x >> 4);
    if (r >= n) return;
    const int ql = threadIdx.x & 15;
    int beg = row_ptr[r], end = row_ptr[r + 1];
    float a[8];
    {
        uint4 u = xw[(size_t)r * 16 + ql];          // self-loop
        a[0]=blo(u.x); a[1]=bhi(u.x); a[2]=blo(u.y); a[3]=bhi(u.y);
        a[4]=blo(u.z); a[5]=bhi(u.z); a[6]=blo(u.w); a[7]=bhi(u.w);
    }
    int j = beg;
    for (; j + 4 <= end; j += 4) {                  // 4 gathers in flight per lane
        int s0 = csr[j], s1 = csr[j+1], s2 = csr[j+2], s3 = csr[j+3];
        uint4 u0 = xw[(size_t)s0 * 16 + ql];
        uint4 u1 = xw[(size_t)s1 * 16 + ql];
        uint4 u2 = xw[(size_t)s2 * 16 + ql];
        uint4 u3 = xw[(size_t)s3 * 16 + ql];
        a[0]+=blo(u0.x)+blo(u1.x)+blo(u2.x)+blo(u3.x); a[1]+=bhi(u0.x)+bhi(u1.x)+bhi(u2.x)+bhi(u3.x);
        a[2]+=blo(u0.y)+blo(u1.y)+blo(u2.y)+blo(u3.y); a[3]+=bhi(u0.y)+bhi(u1.y)+bhi(u2.y)+bhi(u3.y);
        a[4]+=blo(u0.z)+blo(u1.z)+blo(u2.z)+blo(u3.z); a[5]+=bhi(u0.z)+bhi(u1.z)+bhi(u2.z)+bhi(u3.z);
        a[6]+=blo(u0.w)+blo(u1.w)+blo(u2.w)+blo(u3.w); a[7]+=bhi(u0.w)+bhi(u1.w)+bhi(u2.w)+bhi(u3.w);
    }
    for (; j < end; ++j) {
        uint4 u0 = xw[(size_t)csr[j] * 16 + ql];
        a[0]+=blo(u0.x); a[1]+=bhi(u0.x); a[2]+=blo(u0.y); a[3]+=bhi(u0.y);
        a[4]+=blo(u0.z); a[5]+=bhi(u0.z); a[6]+=blo(u0.w); a[7]+=bhi(u0.w);
    }
    float ndr = nd[r], nsr = ns[r];
    float4 b0 = *(const float4*)(b + ql * 8);
    float4 b1 = *(const float4*)(b + ql * 8 + 4);
    uint4 pk;
    pk.x = packbf(fmaxf(a[0]*ndr + b0.x, 0.f) * nsr, fmaxf(a[1]*ndr + b0.y, 0.f) * nsr);
    pk.y = packbf(fmaxf(a[2]*ndr + b0.z, 0.f) * nsr, fmaxf(a[3]*ndr + b0.w, 0.f) * nsr);
    pk.z = packbf(fmaxf(a[4]*ndr + b1.x, 0.f) * nsr, fmaxf(a[5]*ndr + b1.y, 0.f) * nsr);
    pk.w = packbf(fmaxf(a[6]*ndr + b1.z, 0.f) * nsr, fmaxf(a[7]*ndr + b1.w, 0.f) * nsr);
    ((uint4*)(out + (size_t)r * 128))[ql] = pk;
}

// ---------- layer-2 aggregate: one quarter-wave per node, lane = uint2 (4 cols) ----------
__global__ __launch_bounds__(256) void agg_csr64(const int* __restrict__ row_ptr,
        const int* __restrict__ csr, const uint2* __restrict__ xw,
        const float* __restrict__ nd, const float* __restrict__ b,
        float* __restrict__ out, int n)
{
    int r = blockIdx.x * 16 + (threadIdx.x >> 4);
    if (r >= n) return;
    const int ql = threadIdx.x & 15;
    int beg = row_ptr[r], end = row_ptr[r + 1];
    float a[4];
    {
        uint2 u = xw[(size_t)r * 16 + ql];          // self-loop
        a[0]=blo(u.x); a[1]=bhi(u.x); a[2]=blo(u.y); a[3]=bhi(u.y);
    }
    int j = beg;
    for (; j + 4 <= end; j += 4) {
        int s0 = csr[j], s1 = csr[j+1], s2 = csr[j+2], s3 = csr[j+3];
        uint2 u0 = xw[(size_t)s0 * 16 + ql];
        uint2 u1 = xw[(size_t)s1 * 16 + ql];
        uint2 u2 = xw[(size_t)s2 * 16 + ql];
        uint2 u3 = xw[(size_t)s3 * 16 + ql];
        a[0]+=blo(u0.x)+blo(u1.x)+blo(u2.x)+blo(u3.x); a[1]+=bhi(u0.x)+bhi(u1.x)+bhi(u2.x)+bhi(u3.x);
        a[2]+=blo(u0.y)+blo(u1.y)+blo(u2.y)+blo(u3.y); a[3]+=bhi(u0.y)+bhi(u1.y)+bhi(u2.y)+bhi(u3.y);
    }
    for (; j < end; ++j) {
        uint2 u0 = xw[(size_t)csr[j] * 16 + ql];
        a[0]+=blo(u0.x); a[1]+=bhi(u0.x); a[2]+=blo(u0.y); a[3]+=bhi(u0.y);
    }
    float ndr = nd[r];
    float4 bb = *(const float4*)(b + ql * 4);
    float4 o;
    o.x = a[0]*ndr + bb.x;
    o.y = a[1]*ndr + bb.y;
    o.z = a[2]*ndr + bb.z;
    o.w = a[3]*ndr + bb.w;
    *(float4*)(out + (size_t)r * 64 + ql * 4) = o;
}

extern "C" void kernel_launch(void* const* d_in, const int* in_sizes, int n_in,
                              void* d_out, int out_size, void* d_ws, size_t ws_size,
                              hipStream_t stream)
{
    const float* x  = (const float*)d_in[0];   // [N,128] f32
    const int* src  = (const int*)d_in[1];     // [E]
    const int* dst  = (const int*)d_in[2];     // [E]
    const float* W1 = (const float*)d_in[3];   // [128,128] f32
    const float* b1 = (const float*)d_in[4];   // [128] f32
    const float* W2 = (const float*)d_in[5];   // [128,64] f32
    const float* b2 = (const float*)d_in[6];   // [64] f32
    float* out = (float*)d_out;                // [N,64] f32

    const int n = NN, e = NE;
    const int nchunks = n / 16;                // 6250, exact
    const int gemm_grid = (nchunks + 3) / 4;   // 1563

    // workspace layout
    char* p = (char*)d_ws;
    float* ns      = (float*)p; p += (size_t)n * 4;
    float* nd      = (float*)p; p += (size_t)n * 4;
    int*   row_ptr = (int*)p;   p += (size_t)(n + 1) * 4;
    int*   cd      = (int*)p;   p += (size_t)NBUCK * 4;     // cd,cs adjacent: zeroed together
    int*   cs      = (int*)p;   p += (size_t)NBUCK * 4;
    int*   offd    = (int*)p;   p += (size_t)(NBUCK + 1) * 4;
    int*   offs    = (int*)p;   p += (size_t)(NBUCK + 1) * 4;
    int*   curd    = (int*)p;   p += (size_t)NBUCK * 4;
    int*   curs    = (int*)p;   p += (size_t)NBUCK * 4;
    int*   csr     = (int*)p;   p += (size_t)e * 4;
    p = (char*)(((uintptr_t)p + 255) & ~(uintptr_t)255);
    __bf16* bufA   = (__bf16*)p; p += (size_t)128 * n * 2;  // xw1 bf16, then xw2 bf16
    p = (char*)(((uintptr_t)p + 255) & ~(uintptr_t)255);
    __bf16* bufB   = (__bf16*)p;                             // h bf16 [N,128]
    uint*  pairs   = (uint*)bufB;                            // build-phase only
    int*   bsrc    = (int*)bufA;                             // build-phase only

    zero_ints<<<(2 * NBUCK + 255) / 256, 256, 0, stream>>>(cd, 2 * NBUCK);
    coarse_hist<<<256, 256, 0, stream>>>((const int4*)src, (const int4*)dst, cd, cs, e / 4);
    scan_coarse<<<1, 512, 0, stream>>>(cd, cs, offd, offs, curd, curs, row_ptr, n, e);
    part_both<<<NPART, 256, 0, stream>>>(src, dst, curd, curs, pairs, bsrc, e);
    fine_both<<<NBUCK, 256, 0, stream>>>(offd, pairs, offs, bsrc, row_ptr, nd, ns, csr, n);

    // layer 1: xw1 = bf16((x @ W1) * ns) ; h = bf16(relu((xw1[r]+sum nbr)*nd + b1) * ns)
    gemm_mfma<128, true><<<gemm_grid, 256, 0, stream>>>(x, W1, ns, bufA, nchunks);
    agg_csr128<<<(n + 15) / 16, 256, 0, stream>>>(row_ptr, csr, (const uint4*)bufA, nd, ns, b1, bufB, n);

    // layer 2: xw2 = bf16(h @ W2) ; out = (xw2[r]+sum nbr)*nd + b2
    gemm_mfma_bf16<64><<<gemm_grid, 256, 0, stream>>>(bufB, W2, bufA, nchunks);
    agg_csr64<<<(n + 15) / 16, 256, 0, stream>>>(row_ptr, csr, (const uint2*)bufA, nd, b2, out, n);
}